// Round 5
// baseline (191.312 us; speedup 1.0000x reference)
//
#include <hip/hip_runtime.h>

// CGLayer: MAX_L=2, B=2, N=256, TAU=16 — single fused kernel.
// Identity: sum_j of edge-level CG(rep, sph) commutes with the j-sum because
// rep is broadcast along j => per-node work after S[bi][m2] = sum_j s[bi][j][m2].
// Each block = one node bi: stages conn row, computes vmp+S+CG table in LDS,
// does node-level CG + wnl mix, rel-level CG + wrel mix, writes unnormalized
// out; last block (device-scope fence + atomic counter) sums and normalizes.

#define TAU 16

__constant__ double g_FACT[8] = {1.0,1.0,2.0,6.0,24.0,120.0,720.0,5040.0};
__constant__ int g_TRI[15][3] = {
  {0,0,0},{0,1,1},{0,2,2},{1,0,1},{1,1,0},{1,1,1},{1,1,2},{1,2,1},{1,2,2},
  {2,0,2},{2,1,1},{2,1,2},{2,2,0},{2,2,1},{2,2,2}};
__constant__ int g_TRI_OFF[16] = {0,1,10,35,44,53,80,125,170,245,270,315,390,415,490,615};

constexpr int OFF3[27] = {           // [l1*9 + l2*3 + l] -> cg table offset
  0,-1,-1,  -1,1,-1,   -1,-1,10,
  -1,35,-1, 44,53,80,  -1,125,170,
  -1,-1,245,-1,270,315,390,415,490};
constexpr int PAIRS[3][6][2] = {     // (l1,l2) order per output l (reference concat order)
  {{0,0},{1,1},{2,2},{0,0},{0,0},{0,0}},
  {{0,1},{1,0},{1,1},{1,2},{2,1},{2,2}},
  {{0,2},{1,1},{1,2},{2,0},{2,1},{2,2}}};
constexpr int VOFF[3]   = {0,16,64};
constexpr int SOFF[3]   = {0,1,4};
constexpr int OUT_OFF[3]= {0,8192,32768};
constexpr int NPAIR[3]  = {3,6,6};
constexpr int FOFF[9]   = {0,16,32,48,64,80,96,112,128};

__device__ constexpr int RIDX(int l, int mi){ return l==0 ? 0 : (l==1 ? 1+mi : 4+mi); }

__device__ double cg_coef(int j1,int j2,int j3,int m1,int m2,int m3){
  double pre = sqrt((2.0*j3+1.0)*g_FACT[j3+j1-j2]*g_FACT[j3-j1+j2]*g_FACT[j1+j2-j3]/g_FACT[j1+j2+j3+1]);
  pre *= sqrt(g_FACT[j3+m3]*g_FACT[j3-m3]*g_FACT[j1-m1]*g_FACT[j1+m1]*g_FACT[j2-m2]*g_FACT[j2+m2]);
  int kmin = max(0, max(j2-j3-m1, j1-j3+m2));
  int kmax = min(j1+j2-j3, min(j1-m1, j2+m2));
  double s = 0.0;
  for (int k=kmin;k<=kmax;k++){
    double d = g_FACT[k]*g_FACT[j1+j2-j3-k]*g_FACT[j1-m1-k]*g_FACT[j2+m2-k]*g_FACT[j3-j2+m1+k]*g_FACT[j3-j1-m2+k];
    s += (k & 1) ? (-1.0/d) : (1.0/d);
  }
  return pre*s;
}

// one pair's blk rows: all indices compile-time after unroll; cg from LDS (broadcast)
#define BUILD_P(L_, P_) do { \
  constexpr int l1_ = PAIRS[L_][P_][0], l2_ = PAIRS[L_][P_][1]; \
  constexpr int d2_ = 2*l2_+1, dkk_ = 2*(L_)+1; \
  constexpr int coff_ = OFF3[l1_*9+l2_*3+(L_)]; \
  _Pragma("unroll") \
  for (int kk=0; kk<dkk_; kk++) { \
    const int m_ = kk - (L_); \
    float a_ = 0.f; \
    _Pragma("unroll") \
    for (int m1=-l1_; m1<=l1_; m1++) { \
      const int m2 = m_ - m1; \
      if (m2 >= -l2_ && m2 <= l2_) \
        a_ += sh_cg[coff_ + ((m1+l1_)*d2_ + (m2+l2_))*dkk_ + kk] \
              * v_c[RIDX(l1_, m1+l1_)] * v_d[RIDX(l2_, m2+l2_)]; \
    } \
    sh_bm[((P_)*dkk_ + kk)*256 + (t&255)] = a_; \
  } \
} while(0)

__global__ __launch_bounds__(512, 4)
void k_fused(const float* __restrict__ v0, const float* __restrict__ v1, const float* __restrict__ v2,
             const float* __restrict__ s0, const float* __restrict__ s1, const float* __restrict__ s2,
             const float* __restrict__ wnl0, const float* __restrict__ wnl1, const float* __restrict__ wnl2,
             const float* __restrict__ wrel0, const float* __restrict__ wrel1, const float* __restrict__ wrel2,
             const int* __restrict__ conn, int* __restrict__ counter, float* __restrict__ out)
{
  __shared__ __align__(16) float sh_bm[7680];    // blk [30][256] / mix [80][68] / vmp-halves overlay
  __shared__ __align__(16) float sh_wt[2][4096]; // transposed w tile [tc][cd], double-buffered
  __shared__ float sh_cg[616];
  __shared__ float sh_conn[256];
  __shared__ float sh_vmp[144];
  __shared__ float sh_S[9];
  __shared__ float sh_mnl[144];
  __shared__ float sh_rel[480];
  __shared__ float sh_fin[32];
  __shared__ int   sh_last;

  const int t  = threadIdx.x;
  const int bi = blockIdx.x;
  const int b  = bi >> 8;

  // ================= Phase A: conn, vmp, S, CG table =================
  if (t < 256) sh_conn[t] = (float)conn[((size_t)bi<<8) + t];
  __syncthreads();

  if (t < 288) {
    // vmp halves: h=0 -> j 0..127, h=1 -> j 128..255
    const int h = (t >= 144) ? 1 : 0;
    const int tt = t - h*144;
    int l, m, c;
    if (tt < 16)      { l=0; m=0;          c=tt;    }
    else if (tt < 64) { l=1; m=(tt-16)>>4; c=tt&15; }
    else              { l=2; m=(tt-64)>>4; c=tt&15; }
    const float* vl = (l==0) ? v0 : (l==1) ? v1 : v2;
    const int dm = 2*l+1;
    const int stride = dm*TAU;
    const float* base = vl + (((size_t)b*256 + h*128)*dm + m)*TAU + c;
    const float* cr = &sh_conn[h*128];
    float a0=0.f,a1=0.f,a2=0.f,a3=0.f;
    for (int j=0;j<128;j+=4){
      a0 += cr[j+0]*base[(j+0)*stride];
      a1 += cr[j+1]*base[(j+1)*stride];
      a2 += cr[j+2]*base[(j+2)*stride];
      a3 += cr[j+3]*base[(j+3)*stride];
    }
    sh_bm[h*144 + tt] = (a0+a1)+(a2+a3);
  } else if (t < 384) {
    // CG table into LDS (DP Racah)
    for (int s = t-288; s < 615; s += 96) {
      int tr = 0;
      while (s >= g_TRI_OFF[tr+1]) tr++;
      int l1=g_TRI[tr][0], l2=g_TRI[tr][1], l=g_TRI[tr][2];
      int rem = s - g_TRI_OFF[tr];
      int d2 = 2*l2+1, dk = 2*l+1;
      int i1 = rem/(d2*dk); int r2 = rem%(d2*dk); int i2 = r2/dk; int ik = r2%dk;
      int m1=i1-l1, m2=i2-l2, m=ik-l;
      float val = 0.f;
      if (m1+m2 == m) val = (float)cg_coef(l1,l2,l,m1,m2,m);
      sh_cg[s] = val;
    }
  } else if (t >= 448) {
    // S[m] = sum_j s[bi][j][m]; one full wave -> clean shfl reduce
    const int tt = t - 448;
    const float* p0 = s0 + (size_t)bi*256;
    const float* p1 = s1 + (size_t)bi*768;
    const float* p2 = s2 + (size_t)bi*1280;
    float a[9];
    #pragma unroll
    for (int m=0;m<9;m++) a[m]=0.f;
    #pragma unroll
    for (int q=0;q<4;q++){
      const int j = tt + q*64;
      a[0] += p0[j];
      a[1] += p1[3*j+0]; a[2] += p1[3*j+1]; a[3] += p1[3*j+2];
      #pragma unroll
      for (int k=0;k<5;k++) a[4+k] += p2[5*j+k];
    }
    #pragma unroll
    for (int m=0;m<9;m++){
      #pragma unroll
      for (int off=32; off; off>>=1) a[m] += __shfl_xor(a[m], off);
    }
    if (tt == 0) {
      #pragma unroll
      for (int m=0;m<9;m++) sh_S[m] = a[m];
    }
  }
  __syncthreads();
  if (t < 144) sh_vmp[t] = sh_bm[t] + sh_bm[144+t];
  __syncthreads();

  // per-thread vmp fragments (build uses registers + LDS-broadcast cg only)
  const int bc = (t>>4)&15, bd = t&15;
  float v_c[9], v_d[9];
  #pragma unroll
  for (int r=0;r<9;r++){ v_c[r] = sh_vmp[FOFF[r]+bc]; v_d[r] = sh_vmp[FOFF[r]+bd]; }

  const int tg = t>>6, ksub = t&63;    // wave id = tc-pair group; lane = K-chunk
  const int tc0 = tg*2;
  const int tcw = (t&1)*8, cdw = t>>1; // w-transpose staging coords

  // ================= Phase B: node-level CG + wnl mixing -> sh_mnl =================
  #pragma unroll
  for (int l=0; l<3; l++) {
    const int dk = 2*l+1;
    const int n_out = dk*16;
    const int np = NPAIR[l];
    const float* wl = (l==0)?wnl0:(l==1)?wnl1:wnl2;

    // prefetch w tile p=0 (issued early; hides under build VALU)
    float4 ra = *(const float4*)(wl + (size_t)t*8);
    float4 rb = *(const float4*)(wl + (size_t)t*8 + 4);

    if (l == 0) {
      if (t < 256) { BUILD_P(0,0); BUILD_P(0,1); BUILD_P(0,2); }
    } else if (l == 1) {
      if (t < 256) { BUILD_P(1,0); BUILD_P(1,1); BUILD_P(1,2); }
      else         { BUILD_P(1,3); BUILD_P(1,4); BUILD_P(1,5); }
    } else {
      if (t < 256) { BUILD_P(2,0); BUILD_P(2,1); BUILD_P(2,2); }
      else         { BUILD_P(2,3); BUILD_P(2,4); BUILD_P(2,5); }
    }

    float acc[5][2];
    #pragma unroll
    for (int k=0;k<5;k++){ acc[k][0]=0.f; acc[k][1]=0.f; }

    __syncthreads();            // build visible; prior-l sh_bm/sh_wt readers done
    {
      float* wt0 = sh_wt[0];
      #pragma unroll
      for (int i=0;i<4;i++) wt0[(tcw+i)*256 + cdw]   = ((const float*)&ra)[i];
      #pragma unroll
      for (int i=0;i<4;i++) wt0[(tcw+4+i)*256 + cdw] = ((const float*)&rb)[i];
    }
    __syncthreads();            // w tile 0 visible

    int buf = 0;
    for (int p=0; p<np; p++) {
      if (p+1 < np) {           // prefetch next tile under the FMAs
        ra = *(const float4*)(wl + (size_t)(p+1)*4096 + (size_t)t*8);
        rb = *(const float4*)(wl + (size_t)(p+1)*4096 + (size_t)t*8 + 4);
      }
      const float* wt = sh_wt[buf];
      const float4 w0 = *(const float4*)&wt[(tc0  )*256 + ksub*4];
      const float4 w1 = *(const float4*)&wt[(tc0+1)*256 + ksub*4];
      #pragma unroll
      for (int k=0;k<5;k++) if (k < dk) {
        const float4 bk = *(const float4*)&sh_bm[(p*dk+k)*256 + ksub*4];
        acc[k][0] += bk.x*w0.x + bk.y*w0.y + bk.z*w0.z + bk.w*w0.w;
        acc[k][1] += bk.x*w1.x + bk.y*w1.y + bk.z*w1.z + bk.w*w1.w;
      }
      if (p+1 < np) {
        float* wtn = sh_wt[buf^1];
        #pragma unroll
        for (int i=0;i<4;i++) wtn[(tcw+i)*256 + cdw]   = ((const float*)&ra)[i];
        #pragma unroll
        for (int i=0;i<4;i++) wtn[(tcw+4+i)*256 + cdw] = ((const float*)&rb)[i];
      }
      __syncthreads();
      buf ^= 1;
    }

    // K-chunk reduction via LDS scratch overlaid on dead blk region
    #pragma unroll
    for (int k=0;k<5;k++) if (k < dk) {
      sh_bm[(k*16 + tc0  )*68 + ksub] = acc[k][0];
      sh_bm[(k*16 + tc0+1)*68 + ksub] = acc[k][1];
    }
    __syncthreads();
    if (t < n_out) {
      const float* row = &sh_bm[t*68];
      float r0=0.f,r1=0.f,r2=0.f,r3=0.f;
      #pragma unroll
      for (int q=0;q<16;q++){
        const float4 v = *(const float4*)&row[q*4];
        r0+=v.x; r1+=v.y; r2+=v.z; r3+=v.w;
      }
      sh_mnl[VOFF[l]+t] = (r0+r1)+(r2+r3);
    }
    __syncthreads();
  }

  // ================= Phase C: rel-level CG (j-summed sph) + wrel mixing =================
  #pragma unroll
  for (int l=0; l<3; l++) {
    const int dk = 2*l+1;
    const int n_out = dk*16;
    const int k = t >> 4, tc = t & 15;
    const float* wl = (l==0)?wrel0:(l==1)?wrel1:wrel2;
    const int np = NPAIR[l];

    __syncthreads();
    if (t < n_out) {
      #pragma unroll
      for (int p=0; p<6; p++) {
        if (p < np) {
          const int l1 = PAIRS[l][p][0], l2 = PAIRS[l][p][1];
          const int d2 = 2*l2+1;
          const int coff = OFF3[l1*9+l2*3+l];
          const int m = k - l;
          float a = 0.f;
          const int lo = (-l1 > m-l2) ? -l1 : m-l2;
          const int hi = ( l1 < m+l2) ?  l1 : m+l2;
          #pragma unroll
          for (int m1=-2; m1<=2; m1++) {
            if (m1 >= lo && m1 <= hi) {
              const int m2 = m - m1;
              const float C = sh_cg[coff + ((m1+l1)*d2 + (m2+l2))*dk + k];
              a += C * sh_mnl[VOFF[l1] + (m1+l1)*TAU + tc] * sh_S[SOFF[l2] + (m2+l2)];
            }
          }
          sh_rel[(p*dk + k)*TAU + tc] = a;
        }
      }
    }
    __syncthreads();
    if (t < n_out) {
      float acc = 0.f;
      #pragma unroll
      for (int p=0; p<6; p++) {
        if (p < np) {
          #pragma unroll
          for (int c=0; c<16; c++)
            acc += sh_rel[(p*dk + k)*TAU + c] * wl[(p*TAU + c)*TAU + tc];
        }
      }
      out[OUT_OFF[l] + ((size_t)bi*dk + k)*TAU + tc] = acc;
    }
  }

  // ================= Finish: last block sums + normalizes =================
  __threadfence();                       // release: out stores visible device-wide
  if (t == 0) sh_last = (atomicAdd(counter, 1) == 511);
  __syncthreads();
  if (!sh_last) return;

  __threadfence();                       // acquire
  const float4* o4r = (const float4*)out;
  float p0=0.f, p1=0.f, p2=0.f;
  for (int i4=t; i4<18432; i4+=512){
    const float4 v = o4r[i4];
    const float s = (v.x+v.y)+(v.z+v.w);
    if (i4 < 2048) p0 += s; else if (i4 < 8192) p1 += s; else p2 += s;
  }
  #pragma unroll
  for (int off=32; off; off>>=1){
    p0 += __shfl_xor(p0, off); p1 += __shfl_xor(p1, off); p2 += __shfl_xor(p2, off);
  }
  if ((t&63) == 0){ const int w = t>>6; sh_fin[w]=p0; sh_fin[8+w]=p1; sh_fin[16+w]=p2; }
  __syncthreads();
  if (t < 3){
    const float* f = &sh_fin[t*8];
    sh_fin[24+t] = ((f[0]+f[1])+(f[2]+f[3])) + ((f[4]+f[5])+(f[6]+f[7]));
  }
  __syncthreads();
  const float d0 = sh_fin[24], d1 = sh_fin[25], d2 = sh_fin[26];
  float4* o4 = (float4*)out;
  for (int i4=t; i4<18432; i4+=512){
    float4 v = o4[i4];
    const float dd = (i4 < 2048) ? d0 : ((i4 < 8192) ? d1 : d2);
    v.x/=dd; v.y/=dd; v.z/=dd; v.w/=dd;
    o4[i4] = v;
  }
}

extern "C" void kernel_launch(void* const* d_in, const int* in_sizes, int n_in,
                              void* d_out, int out_size, void* d_ws, size_t ws_size,
                              hipStream_t stream) {
  // setup_inputs order: v0,s0,wnl0,wrel0, v1,s1,wnl1,wrel1, v2,s2,wnl2,wrel2, conn
  const float* v0    = (const float*)d_in[0];
  const float* s0    = (const float*)d_in[1];
  const float* wnl0  = (const float*)d_in[2];
  const float* wrel0 = (const float*)d_in[3];
  const float* v1    = (const float*)d_in[4];
  const float* s1    = (const float*)d_in[5];
  const float* wnl1  = (const float*)d_in[6];
  const float* wrel1 = (const float*)d_in[7];
  const float* v2    = (const float*)d_in[8];
  const float* s2    = (const float*)d_in[9];
  const float* wnl2  = (const float*)d_in[10];
  const float* wrel2 = (const float*)d_in[11];
  const int*   conn  = (const int*)d_in[12];
  float* out = (float*)d_out;
  int* counter = (int*)d_ws;

  hipMemsetAsync(counter, 0, sizeof(int), stream);
  k_fused<<<512, 512, 0, stream>>>(v0, v1, v2, s0, s1, s2,
                                   wnl0, wnl1, wnl2, wrel0, wrel1, wrel2,
                                   conn, counter, out);
}

// Round 6
// 134.114 us; speedup vs baseline: 1.4265x; 1.4265x over previous
//
#include <hip/hip_runtime.h>

// CGLayer: MAX_L=2, B=2, N=256, TAU=16 — 3-kernel pipeline (split proven faster than fused).
// Identity: sum_j of edge-level CG(rep, sph) commutes with the j-sum because rep is
// broadcast along j => per-node work after S[bi][m2] = sum_j s[bi][j][m2].
// k_prep: vmp + S + CG table + wnl transpose + zero sums.
// k_main: node-level CG + wnl mix (pre-transposed, coalesced), rel-level CG + wrel mix.
// k_norm: divide by per-l totals.

#define TAU 16

// ws layout (floats)
#define CG_OFF   0        // 615
#define SUMS_OFF 640      // 3
#define VMP_OFF  1024     // 512*144
#define S_OFF    74752    // 512*16 (9 used)
#define WT_OFF   82944    // 15*4096 transposed wnl tiles: [tile][tc][cd]

__constant__ double g_FACT[8] = {1.0,1.0,2.0,6.0,24.0,120.0,720.0,5040.0};
__constant__ int g_TRI[15][3] = {
  {0,0,0},{0,1,1},{0,2,2},{1,0,1},{1,1,0},{1,1,1},{1,1,2},{1,2,1},{1,2,2},
  {2,0,2},{2,1,1},{2,1,2},{2,2,0},{2,2,1},{2,2,2}};
__constant__ int g_TRI_OFF[16] = {0,1,10,35,44,53,80,125,170,245,270,315,390,415,490,615};

constexpr int OFF3[27] = {           // [l1*9 + l2*3 + l] -> cg table offset
  0,-1,-1,  -1,1,-1,   -1,-1,10,
  -1,35,-1, 44,53,80,  -1,125,170,
  -1,-1,245,-1,270,315,390,415,490};
constexpr int PAIRS[3][6][2] = {     // (l1,l2) order per output l (reference concat order)
  {{0,0},{1,1},{2,2},{0,0},{0,0},{0,0}},
  {{0,1},{1,0},{1,1},{1,2},{2,1},{2,2}},
  {{0,2},{1,1},{1,2},{2,0},{2,1},{2,2}}};
constexpr int VOFF[3]   = {0,16,64};
constexpr int SOFF[3]   = {0,1,4};
constexpr int OUT_OFF[3]= {0,8192,32768};
constexpr int NPAIR[3]  = {3,6,6};
constexpr int FOFF[9]   = {0,16,32,48,64,80,96,112,128};

__device__ constexpr int RIDX(int l, int mi){ return l==0 ? 0 : (l==1 ? 1+mi : 4+mi); }

__device__ double cg_coef(int j1,int j2,int j3,int m1,int m2,int m3){
  double pre = sqrt((2.0*j3+1.0)*g_FACT[j3+j1-j2]*g_FACT[j3-j1+j2]*g_FACT[j1+j2-j3]/g_FACT[j1+j2+j3+1]);
  pre *= sqrt(g_FACT[j3+m3]*g_FACT[j3-m3]*g_FACT[j1-m1]*g_FACT[j1+m1]*g_FACT[j2-m2]*g_FACT[j2+m2]);
  int kmin = max(0, max(j2-j3-m1, j1-j3+m2));
  int kmax = min(j1+j2-j3, min(j1-m1, j2+m2));
  double s = 0.0;
  for (int k=kmin;k<=kmax;k++){
    double d = g_FACT[k]*g_FACT[j1+j2-j3-k]*g_FACT[j1-m1-k]*g_FACT[j2+m2-k]*g_FACT[j3-j2+m1+k]*g_FACT[j3-j1-m2+k];
    s += (k & 1) ? (-1.0/d) : (1.0/d);
  }
  return pre*s;
}

// ---------------- K1: vmp + S + CG table + wnl transpose + zero sums ----------------
__global__ __launch_bounds__(512)
void k_prep(const float* __restrict__ v0, const float* __restrict__ v1, const float* __restrict__ v2,
            const float* __restrict__ s0, const float* __restrict__ s1, const float* __restrict__ s2,
            const float* __restrict__ wnl0, const float* __restrict__ wnl1, const float* __restrict__ wnl2,
            const int* __restrict__ conn, float* __restrict__ ws)
{
  __shared__ float sh_conn[256];
  __shared__ float sh_v[2][144];
  __shared__ float sh_red[4][9];
  const int t = threadIdx.x;
  const int blk = blockIdx.x;

  if (blk < 512) {
    // vmp[bi][f] = sum_j conn[bi,j] * v[b,j,f]; 2 j-halves x 144 feats, 8-acc ILP
    const int bi = blk, b = bi >> 8;
    if (t < 256) sh_conn[t] = (float)conn[((size_t)bi<<8) + t];
    __syncthreads();
    const int h = t >> 8, tt = t & 255;
    if (tt < 144) {
      int l, m, c;
      if (tt < 16)      { l=0; m=0;          c=tt;    }
      else if (tt < 64) { l=1; m=(tt-16)>>4; c=tt&15; }
      else              { l=2; m=(tt-64)>>4; c=tt&15; }
      const float* vl = (l==0) ? v0 : (l==1) ? v1 : v2;
      const int dm = 2*l+1;
      const int stride = dm*TAU;
      const float* base = vl + (((size_t)b*256 + h*128)*dm + m)*TAU + c;
      const float* cr = &sh_conn[h*128];
      float a[8];
      #pragma unroll
      for (int q=0;q<8;q++) a[q]=0.f;
      for (int j=0;j<128;j+=8){
        #pragma unroll
        for (int q=0;q<8;q++) a[q] += cr[j+q]*base[(j+q)*stride];
      }
      sh_v[h][tt] = ((a[0]+a[1])+(a[2]+a[3])) + ((a[4]+a[5])+(a[6]+a[7]));
    }
    __syncthreads();
    if (t < 144) ws[VMP_OFF + (size_t)bi*144 + t] = sh_v[0][t] + sh_v[1][t];
  } else if (blk < 1024) {
    // S[bi][9] = sum_j s_l[bi][j][m] (coalesced, 4-wave shfl reduce)
    const int bi = blk - 512;
    if (t < 256) {
      const float* p0 = s0 + (size_t)bi*256;
      const float* p1 = s1 + (size_t)bi*768;
      const float* p2 = s2 + (size_t)bi*1280;
      float a[9];
      a[0] = p0[t];
      a[1] = p1[3*t+0]; a[2] = p1[3*t+1]; a[3] = p1[3*t+2];
      #pragma unroll
      for (int k=0;k<5;k++) a[4+k] = p2[5*t+k];
      #pragma unroll
      for (int m=0;m<9;m++){
        #pragma unroll
        for (int off=32; off; off>>=1) a[m] += __shfl_xor(a[m], off);
      }
      const int wid = t>>6, lane = t&63;
      if (lane == 0) {
        #pragma unroll
        for (int m=0;m<9;m++) sh_red[wid][m] = a[m];
      }
    }
    __syncthreads();
    if (t < 9) ws[S_OFF + (size_t)(blk-512)*16 + t] = sh_red[0][t]+sh_red[1][t]+sh_red[2][t]+sh_red[3][t];
  } else if (blk < 1039) {
    // transpose one wnl tile: wT[tc][cd] = w[cd][tc]
    const int tile = blk - 1024;   // 0..14: 0-2 wnl0, 3-8 wnl1, 9-14 wnl2
    const float* src = (tile<3) ? (wnl0 + (size_t)tile*4096)
                     : (tile<9) ? (wnl1 + (size_t)(tile-3)*4096)
                                : (wnl2 + (size_t)(tile-9)*4096);
    float* dst = ws + WT_OFF + (size_t)tile*4096;
    if (t < 256) {
      const int cd = t;
      const float4 r0 = *(const float4*)(src + cd*16);
      const float4 r1 = *(const float4*)(src + cd*16 + 4);
      const float4 r2 = *(const float4*)(src + cd*16 + 8);
      const float4 r3 = *(const float4*)(src + cd*16 + 12);
      dst[ 0*256+cd]=r0.x; dst[ 1*256+cd]=r0.y; dst[ 2*256+cd]=r0.z; dst[ 3*256+cd]=r0.w;
      dst[ 4*256+cd]=r1.x; dst[ 5*256+cd]=r1.y; dst[ 6*256+cd]=r1.z; dst[ 7*256+cd]=r1.w;
      dst[ 8*256+cd]=r2.x; dst[ 9*256+cd]=r2.y; dst[10*256+cd]=r2.z; dst[11*256+cd]=r2.w;
      dst[12*256+cd]=r3.x; dst[13*256+cd]=r3.y; dst[14*256+cd]=r3.z; dst[15*256+cd]=r3.w;
    }
  } else {
    // CG table (DP Racah) + zero sums
    if (t < 128) {
      for (int s = t; s < 615; s += 128) {
        int tr = 0;
        while (s >= g_TRI_OFF[tr+1]) tr++;
        int l1=g_TRI[tr][0], l2=g_TRI[tr][1], l=g_TRI[tr][2];
        int rem = s - g_TRI_OFF[tr];
        int d2 = 2*l2+1, dk = 2*l+1;
        int i1 = rem/(d2*dk); int r2 = rem%(d2*dk); int i2 = r2/dk; int ik = r2%dk;
        int m1=i1-l1, m2=i2-l2, m=ik-l;
        float val = 0.f;
        if (m1+m2 == m) val = (float)cg_coef(l1,l2,l,m1,m2,m);
        ws[CG_OFF + s] = val;
      }
    }
    if (t >= 200 && t < 203) ws[SUMS_OFF + (t-200)] = 0.f;
  }
}

// ---------------- K2 helpers ----------------
template<int L, int P>
__device__ __forceinline__ void build_p(float* __restrict__ dst, const float* __restrict__ cgt,
                                        const float (&v_c)[9], const float (&v_d)[9], int t){
  constexpr int l1 = PAIRS[L][P][0], l2 = PAIRS[L][P][1];
  constexpr int d2 = 2*l2+1, dkk = 2*L+1;
  constexpr int coff = OFF3[l1*9+l2*3+L];
  #pragma unroll
  for (int kk=0; kk<dkk; kk++){
    const int m = kk - L;
    float a = 0.f;
    #pragma unroll
    for (int m1=-l1; m1<=l1; m1++){
      const int m2 = m - m1;
      if (m2 >= -l2 && m2 <= l2)
        a += cgt[coff + ((m1+l1)*d2 + (m2+l2))*dkk + kk] * v_c[RIDX(l1,m1+l1)] * v_d[RIDX(l2,m2+l2)];
    }
    dst[kk*256 + t] = a;   // blk[kk][cd=t]
  }
}

template<int L>
__device__ __forceinline__ void mix_p(const float* __restrict__ wrow, const float* __restrict__ bb,
                                      float (&acc)[2*L+1][2], int ksub){
  const float4 w0 = *(const float4*)(wrow);          // wT[tc0  ][4k..4k+3]
  const float4 w1 = *(const float4*)(wrow + 256);    // wT[tc0+1][4k..4k+3]
  #pragma unroll
  for (int k=0;k<2*L+1;k++){
    const float4 bk = *(const float4*)&bb[k*256 + ksub*4];
    acc[k][0] += bk.x*w0.x + bk.y*w0.y + bk.z*w0.z + bk.w*w0.w;
    acc[k][1] += bk.x*w1.x + bk.y*w1.y + bk.z*w1.z + bk.w*w1.w;
  }
}

// one output-l of phase B: build/mix software pipeline over pairs, butterfly K-reduce
template<int L>
__device__ __forceinline__ void phaseB(const float* __restrict__ cgt, const float* __restrict__ wt,
                                       const float (&v_c)[9], const float (&v_d)[9],
                                       float* __restrict__ b0, float* __restrict__ b1,
                                       float* __restrict__ sh_mnl, int t, int ksub, int tc0){
  constexpr int NP = NPAIR[L];
  constexpr int DK = 2*L+1;
  float acc[DK][2];
  #pragma unroll
  for (int k=0;k<DK;k++){ acc[k][0]=0.f; acc[k][1]=0.f; }
  const float* wbase = wt + (size_t)tc0*256 + ksub*4;

  if (t < 256) build_p<L,0>(b0, cgt, v_c, v_d, t);
  __syncthreads();
  if (t < 256) build_p<L,1>(b1, cgt, v_c, v_d, t);
  mix_p<L>(wbase + 0*4096, b0, acc, ksub);
  __syncthreads();
  if (t < 256) build_p<L,2>(b0, cgt, v_c, v_d, t);
  mix_p<L>(wbase + 1*4096, b1, acc, ksub);
  __syncthreads();
  if constexpr (NP == 3) {
    mix_p<L>(wbase + 2*4096, b0, acc, ksub);
    __syncthreads();
  } else {
    if (t < 256) build_p<L,3>(b1, cgt, v_c, v_d, t);
    mix_p<L>(wbase + 2*4096, b0, acc, ksub);
    __syncthreads();
    if (t < 256) build_p<L,4>(b0, cgt, v_c, v_d, t);
    mix_p<L>(wbase + 3*4096, b1, acc, ksub);
    __syncthreads();
    if (t < 256) build_p<L,5>(b1, cgt, v_c, v_d, t);
    mix_p<L>(wbase + 4*4096, b0, acc, ksub);
    __syncthreads();
    mix_p<L>(wbase + 5*4096, b1, acc, ksub);
    __syncthreads();
  }
  // butterfly over the 64 K-chunk lanes; every lane ends with the totals
  #pragma unroll
  for (int k=0;k<DK;k++){
    #pragma unroll
    for (int off=32; off; off>>=1){
      acc[k][0] += __shfl_xor(acc[k][0], off);
      acc[k][1] += __shfl_xor(acc[k][1], off);
    }
  }
  if (ksub == 0) {
    #pragma unroll
    for (int k=0;k<DK;k++){
      sh_mnl[VOFF[L] + k*16 + tc0    ] = acc[k][0];
      sh_mnl[VOFF[L] + k*16 + tc0 + 1] = acc[k][1];
    }
  }
}

// ---------------- K2: per-node CG products + mixing + sums ----------------
__global__ __launch_bounds__(512, 4)
void k_main(const float* __restrict__ wrel0, const float* __restrict__ wrel1, const float* __restrict__ wrel2,
            const float* __restrict__ ws, float* __restrict__ out, float* __restrict__ sums)
{
  __shared__ __align__(16) float sh_b0[1280];   // double-buffered CG blocks [dk][256]
  __shared__ __align__(16) float sh_b1[1280];
  __shared__ float sh_mnl[144];
  __shared__ float sh_S[9];
  __shared__ float sh_rel[480];
  __shared__ float sh_red[8];

  const int t  = threadIdx.x;
  const int bi = blockIdx.x;
  const float* __restrict__ cgt = ws + CG_OFF;

  // per-thread vmp fragments (registers only)
  const int bc = (t>>4)&15, bd = t&15;
  float v_c[9], v_d[9];
  {
    const float* vb = ws + VMP_OFF + (size_t)bi*144;
    #pragma unroll
    for (int r=0;r<9;r++){ v_c[r] = vb[FOFF[r]+bc]; v_d[r] = vb[FOFF[r]+bd]; }
  }
  if (t < 9) sh_S[t] = ws[S_OFF + (size_t)bi*16 + t];

  const int tg = t>>6, ksub = t&63;  // wave = tc-pair, lane = K-chunk
  const int tc0 = tg*2;

  // -------- Phase B --------
  phaseB<0>(cgt, ws + WT_OFF +     0, v_c, v_d, sh_b0, sh_b1, sh_mnl, t, ksub, tc0);
  phaseB<1>(cgt, ws + WT_OFF + 12288, v_c, v_d, sh_b0, sh_b1, sh_mnl, t, ksub, tc0);
  phaseB<2>(cgt, ws + WT_OFF + 36864, v_c, v_d, sh_b0, sh_b1, sh_mnl, t, ksub, tc0);

  // -------- Phase C: rel-level CG (j-summed sph) + wrel mixing --------
  #pragma unroll
  for (int l=0; l<3; l++) {
    const int dk = 2*l+1;
    const int n_out = dk*16;
    const int k = t >> 4, tc = t & 15;
    const float* wl = (l==0)?wrel0:(l==1)?wrel1:wrel2;
    const int np = NPAIR[l];

    __syncthreads();
    if (t < n_out) {
      #pragma unroll
      for (int p=0; p<6; p++) {
        if (p < np) {
          const int l1 = PAIRS[l][p][0], l2 = PAIRS[l][p][1];
          const int d2 = 2*l2+1;
          const int coff = OFF3[l1*9+l2*3+l];
          const int m = k - l;
          float a = 0.f;
          const int lo = (-l1 > m-l2) ? -l1 : m-l2;
          const int hi = ( l1 < m+l2) ?  l1 : m+l2;
          #pragma unroll
          for (int m1=-2; m1<=2; m1++) {
            if (m1 >= lo && m1 <= hi) {
              const int m2 = m - m1;
              const float C = cgt[coff + ((m1+l1)*d2 + (m2+l2))*dk + k];
              a += C * sh_mnl[VOFF[l1] + (m1+l1)*TAU + tc] * sh_S[SOFF[l2] + (m2+l2)];
            }
          }
          sh_rel[(p*dk + k)*TAU + tc] = a;
        }
      }
    }
    __syncthreads();
    float acc = 0.f;
    if (t < n_out) {
      #pragma unroll
      for (int p=0; p<6; p++) {
        if (p < np) {
          #pragma unroll
          for (int c=0; c<16; c++)
            acc += sh_rel[(p*dk + k)*TAU + c] * wl[(p*TAU + c)*TAU + tc];
        }
      }
    }
    float x = acc;
    #pragma unroll
    for (int off=32; off; off>>=1) x += __shfl_xor(x, off);
    if ((t&63) == 0) sh_red[t>>6] = x;
    __syncthreads();
    if (t == 0) {
      float s = 0.f;
      #pragma unroll
      for (int w=0; w<8; w++) s += sh_red[w];
      atomicAdd(&sums[l], s);
    }
    if (t < n_out) out[OUT_OFF[l] + ((size_t)bi*dk + k)*TAU + tc] = acc;
  }
}

// ---------------- K3: normalize ----------------
__global__ void k_norm(float* __restrict__ out, const float* __restrict__ sums){
  int idx = blockIdx.x*blockDim.x + threadIdx.x;
  if (idx >= 73728) return;
  int l = (idx < 8192) ? 0 : (idx < 32768) ? 1 : 2;
  out[idx] = out[idx] / sums[l];
}

extern "C" void kernel_launch(void* const* d_in, const int* in_sizes, int n_in,
                              void* d_out, int out_size, void* d_ws, size_t ws_size,
                              hipStream_t stream) {
  // setup_inputs order: v0,s0,wnl0,wrel0, v1,s1,wnl1,wrel1, v2,s2,wnl2,wrel2, conn
  const float* v0    = (const float*)d_in[0];
  const float* s0    = (const float*)d_in[1];
  const float* wnl0  = (const float*)d_in[2];
  const float* wrel0 = (const float*)d_in[3];
  const float* v1    = (const float*)d_in[4];
  const float* s1    = (const float*)d_in[5];
  const float* wnl1  = (const float*)d_in[6];
  const float* wrel1 = (const float*)d_in[7];
  const float* v2    = (const float*)d_in[8];
  const float* s2    = (const float*)d_in[9];
  const float* wnl2  = (const float*)d_in[10];
  const float* wrel2 = (const float*)d_in[11];
  const int*   conn  = (const int*)d_in[12];
  float* out = (float*)d_out;
  float* ws  = (float*)d_ws;
  float* sums = ws + SUMS_OFF;

  k_prep<<<1040, 512, 0, stream>>>(v0, v1, v2, s0, s1, s2,
                                   wnl0, wnl1, wnl2, conn, ws);
  k_main<<<512, 512, 0, stream>>>(wrel0, wrel1, wrel2, ws, out, sums);
  k_norm<<<288, 256, 0, stream>>>(out, sums);
}